// Round 4
// baseline (88.908 us; speedup 1.0000x reference)
//
#include <hip/hip_runtime.h>

typedef unsigned int u32;
typedef unsigned short u16;
typedef __attribute__((ext_vector_type(4))) unsigned int u32x4;
typedef __attribute__((ext_vector_type(8))) short s16x8;
typedef __attribute__((ext_vector_type(16))) float f32x16;
typedef __attribute__((ext_vector_type(4))) float f32x4;

__device__ __forceinline__ u32 mono(float f) {
    u32 u = __float_as_uint(f);
    return (u & 0x80000000u) ? ~u : (u | 0x80000000u);
}
__device__ __forceinline__ float unmono(u32 k) {
    return __uint_as_float((k & 0x80000000u) ? (k & 0x7fffffffu) : ~k);
}
// bf16 RNE of a, returned as f32 bit pattern (low 16 cleared)
__device__ __forceinline__ u32 rne_hi(float a) {
    u32 u = __float_as_uint(a);
    return (u + 0x7FFFu + ((u >> 16) & 1u)) & 0xFFFF0000u;
}

__global__ void k0_init(u32* __restrict__ keys) {
    int idx = blockIdx.x * 256 + threadIdx.x;
    if (idx < 8192) keys[idx] = 0u;   // mono-space -inf
}

// Cooperative split-bf16 MFMA point-feature kernel.
// 1024 blocks x 256 threads (4 waves); block = 8 groups of 64 points (one batch
// slice). Stage: all threads do layer1 fp32 (thread = (point, k-quarter)),
// RNE-hi/exact-lo split, v_perm pack, write double-buffered LDS planes.
// Compute: wave = (m = wid>>1, nt-pair = wid&1): W2 frags 64 VGPR/wave,
// 24 mfma_f32_32x32x16_bf16 per group per wave, running max from C frags
// (col = feature). b2 folded into k2 (max(x+b) = max(x)+b).
__global__ __launch_bounds__(256, 4) void k1_pointfeat(
    const float* __restrict__ x, const float* __restrict__ s,
    const float* __restrict__ W1, const float* __restrict__ b1,
    const float* __restrict__ W2, u32* __restrict__ keys)
{
    // [buf][plane][pt][36 u32]; row stride 36 u32 = 144B (16B-mult, conflict-free)
    __shared__ __align__(16) u32 Hlds[2 * 2 * 64 * 36];
    const int tid   = threadIdx.x;
    const int lane  = tid & 63;
    const int point = tid & 63;
    const int kq    = __builtin_amdgcn_readfirstlane(tid >> 6); // wave id, uniform
    const int cl    = lane & 31;
    const int kg    = lane >> 5;
    const int mrow  = (kq >> 1) * 32;
    const int ntp   = (kq & 1) * 2;

    const int p0 = blockIdx.x * 512;      // 512 consecutive points per block
    const int b  = blockIdx.x >> 4;       // 16 blocks per batch

    // ---- W2 split fragments for this wave's two nt tiles (resident) ----
    s16x8 wh[2][4], wl[2][4];
    #pragma unroll
    for (int p = 0; p < 2; ++p)
        #pragma unroll
        for (int sl = 0; sl < 4; ++sl)
            #pragma unroll
            for (int j = 0; j < 8; ++j) {
                float f = W2[(sl * 16 + kg * 8 + j) * 128 + (ntp + p) * 32 + cl];
                u32 hb = rne_hi(f);
                float lo = f - __uint_as_float(hb);
                u32 lb = rne_hi(lo);
                wh[p][sl][j] = (short)(hb >> 16);
                wl[p][sl][j] = (short)(lb >> 16);
            }

    float rmax0 = -3.402823466e38f, rmax1 = -3.402823466e38f;

    float px, py, pz, pw;
    {
        const int gp = p0 + point;
        px = x[(size_t)gp * 3 + 0]; py = x[(size_t)gp * 3 + 1];
        pz = x[(size_t)gp * 3 + 2]; pw = s[gp];
    }

    #pragma unroll 2
    for (int g = 0; g < 8; ++g) {
        // ---- stage group g into buf (g&1) ----
        {
            u32 hp[8], lp[8];
            #pragma unroll
            for (int c = 0; c < 8; ++c) {
                const int k0 = kq * 16 + c * 2;
                float a0 = fmaf(px, W1[k0],
                           fmaf(py, W1[64 + k0],
                           fmaf(pz, W1[128 + k0],
                           fmaf(pw, W1[192 + k0], b1[k0]))));
                float a1 = fmaf(px, W1[k0 + 1],
                           fmaf(py, W1[65 + k0],
                           fmaf(pz, W1[129 + k0],
                           fmaf(pw, W1[193 + k0], b1[k0 + 1]))));
                a0 = a0 > 0.f ? a0 : 0.f;
                a1 = a1 > 0.f ? a1 : 0.f;
                u32 h0 = rne_hi(a0), h1 = rne_hi(a1);
                float l0 = a0 - __uint_as_float(h0);
                float l1 = a1 - __uint_as_float(h1);
                // low16 = bf16(a0), high16 = bf16(a1)
                hp[c] = __builtin_amdgcn_perm(h1, h0, 0x07060302u);
                lp[c] = __builtin_amdgcn_perm(__float_as_uint(l1),
                                              __float_as_uint(l0), 0x07060302u);
            }
            u32* Hw = &Hlds[(g & 1) * 4608 + point * 36 + kq * 8];
            u32x4 v0 = {hp[0], hp[1], hp[2], hp[3]};
            u32x4 v1 = {hp[4], hp[5], hp[6], hp[7]};
            u32x4 v2 = {lp[0], lp[1], lp[2], lp[3]};
            u32x4 v3 = {lp[4], lp[5], lp[6], lp[7]};
            *(u32x4*)(Hw)            = v0;
            *(u32x4*)(Hw + 4)        = v1;
            *(u32x4*)(Hw + 2304)     = v2;
            *(u32x4*)(Hw + 2304 + 4) = v3;
        }
        __syncthreads();
        // prefetch next group's coords (hides HBM latency under MFMA)
        if (g < 7) {
            const int gp = p0 + (g + 1) * 64 + point;
            px = x[(size_t)gp * 3 + 0]; py = x[(size_t)gp * 3 + 1];
            pz = x[(size_t)gp * 3 + 2]; pw = s[gp];
        }
        // ---- compute group g from buf (g&1) ----
        const u32* Hb = &Hlds[(g & 1) * 4608];
        f32x16 acc0 = {}, acc1 = {};
        __builtin_amdgcn_s_setprio(1);
        #pragma unroll
        for (int sl = 0; sl < 4; ++sl) {
            s16x8 ahi = *(const s16x8*)(Hb + (mrow + cl) * 36 + sl * 8 + kg * 4);
            s16x8 alo = *(const s16x8*)(Hb + 2304 + (mrow + cl) * 36 + sl * 8 + kg * 4);
            acc0 = __builtin_amdgcn_mfma_f32_32x32x16_bf16(ahi, wh[0][sl], acc0, 0, 0, 0);
            acc1 = __builtin_amdgcn_mfma_f32_32x32x16_bf16(ahi, wh[1][sl], acc1, 0, 0, 0);
            acc0 = __builtin_amdgcn_mfma_f32_32x32x16_bf16(ahi, wl[0][sl], acc0, 0, 0, 0);
            acc1 = __builtin_amdgcn_mfma_f32_32x32x16_bf16(ahi, wl[1][sl], acc1, 0, 0, 0);
            acc0 = __builtin_amdgcn_mfma_f32_32x32x16_bf16(alo, wh[0][sl], acc0, 0, 0, 0);
            acc1 = __builtin_amdgcn_mfma_f32_32x32x16_bf16(alo, wh[1][sl], acc1, 0, 0, 0);
        }
        __builtin_amdgcn_s_setprio(0);
        #pragma unroll
        for (int r = 0; r < 16; ++r) {
            rmax0 = fmaxf(rmax0, acc0[r]);
            rmax1 = fmaxf(rmax1, acc1[r]);
        }
        // no trailing sync needed: next iter writes the OTHER buffer, and the
        // iter-(g+1) sync orders its compute; writes to THIS buffer only occur
        // at iter g+2, after everyone passed the g+1 sync.
    }

    rmax0 = fmaxf(rmax0, __shfl_xor(rmax0, 32, 64));
    rmax1 = fmaxf(rmax1, __shfl_xor(rmax1, 32, 64));
    if (lane < 32) {
        atomicMax(&keys[b * 128 + (ntp + 0) * 32 + cl], mono(rmax0));
        atomicMax(&keys[b * 128 + (ntp + 1) * 32 + cl], mono(rmax1));
    }
}

// One block per batch: head MLP + VQ. Adds folded-out b2; writes per-batch
// loss partial to ws_loss.
__global__ __launch_bounds__(512) void k2_head(
    const u32* __restrict__ keys, const float* __restrict__ b2,
    const float* __restrict__ e,
    const float* __restrict__ W3, const float* __restrict__ b3,
    const float* __restrict__ W4, const float* __restrict__ b4,
    const float* __restrict__ cb, float* __restrict__ out,
    float* __restrict__ ws_loss)
{
    const int b = blockIdx.x, tid = threadIdx.x;
    __shared__ float comb[640];
    __shared__ float psum[512];
    __shared__ float hid[256];
    __shared__ float ze[128];
    __shared__ float red_d[512];
    __shared__ int   red_i[512];
    __shared__ float lred[128];
    __shared__ float zzs;

    if (tid < 128) comb[tid] = unmono(keys[b * 128 + tid]) + b2[tid];
    comb[128 + tid] = e[b * 512 + tid];
    __syncthreads();

    // hidden = relu(comb @ W3 + b3), i-range split 2 ways
    {
        const int u = tid & 255, part = tid >> 8;
        float a = part ? 0.f : b3[u];
        const int i0 = part * 320;
        #pragma unroll 4
        for (int i = i0; i < i0 + 320; ++i) a = fmaf(comb[i], W3[i * 256 + u], a);
        psum[part * 256 + u] = a;
    }
    __syncthreads();
    if (tid < 256) {
        float hv = psum[tid] + psum[256 + tid];
        hid[tid] = hv > 0.f ? hv : 0.f;
    }
    __syncthreads();

    // z_e = hid @ W4 + b4
    if (tid < 128) {
        float a = b4[tid];
        #pragma unroll 4
        for (int i = 0; i < 256; ++i) a = fmaf(hid[i], W4[i * 128 + tid], a);
        ze[tid] = a;
        out[8192 + b * 128 + tid] = a;
    }
    __syncthreads();

    if (tid < 64) {
        float t = ze[tid] * ze[tid] + ze[tid + 64] * ze[tid + 64];
        #pragma unroll
        for (int d = 1; d < 64; d <<= 1) t += __shfl_xor(t, d, 64);
        if (tid == 0) zzs = t;
    }
    __syncthreads();

    // dists: one code per thread, float4 codebook loads
    {
        float dot = 0.f, cc = 0.f;
        const f32x4* __restrict__ cp = (const f32x4*)(cb + (size_t)tid * 128);
        #pragma unroll 8
        for (int k4 = 0; k4 < 32; ++k4) {
            f32x4 v = cp[k4];
            dot = fmaf(ze[k4 * 4 + 0], v.x, dot);
            cc  = fmaf(v.x, v.x, cc);
            dot = fmaf(ze[k4 * 4 + 1], v.y, dot);
            cc  = fmaf(v.y, v.y, cc);
            dot = fmaf(ze[k4 * 4 + 2], v.z, dot);
            cc  = fmaf(v.z, v.z, cc);
            dot = fmaf(ze[k4 * 4 + 3], v.w, dot);
            cc  = fmaf(v.w, v.w, cc);
        }
        red_d[tid] = zzs - 2.f * dot + cc;
        red_i[tid] = tid;
    }
    __syncthreads();

    // argmin (tie -> lowest index, = np.argmin)
    for (int sft = 256; sft >= 1; sft >>= 1) {
        if (tid < sft) {
            float da = red_d[tid], db = red_d[tid + sft];
            int   ia = red_i[tid], ib = red_i[tid + sft];
            if (db < da || (db == da && ib < ia)) { red_d[tid] = db; red_i[tid] = ib; }
        }
        __syncthreads();
    }
    const int bc = red_i[0];

    if (tid < 128) {
        float zq  = cb[(size_t)bc * 128 + tid];
        float zev = ze[tid];
        out[b * 128 + tid] = zev + (zq - zev);   // z_q_st
        float d = zq - zev;
        lred[tid] = d * d;
    }
    if (tid == 0) out[16386 + b] = (float)bc;
    __syncthreads();
    if (tid < 64) {
        float t = lred[tid] + lred[tid + 64];
        #pragma unroll
        for (int d = 1; d < 64; d <<= 1) t += __shfl_xor(t, d, 64);
        if (tid == 0) ws_loss[b] = t;            // per-batch sum of (zq-ze)^2
    }
}

// Single-wave loss finalize.
__global__ void k3_loss(const float* __restrict__ ws_loss, float* __restrict__ out)
{
    const int t = threadIdx.x;   // 64 threads
    float v = ws_loss[t];
    #pragma unroll
    for (int d = 1; d < 64; d <<= 1) v += __shfl_xor(v, d, 64);
    if (t == 0) {
        float m = v / 8192.f;
        out[16384] = m;   // codebook_loss
        out[16385] = m;   // commitment_loss (numerically identical)
    }
}

extern "C" void kernel_launch(void* const* d_in, const int* in_sizes, int n_in,
                              void* d_out, int out_size, void* d_ws, size_t ws_size,
                              hipStream_t stream) {
    const float* x  = (const float*)d_in[0];
    const float* s  = (const float*)d_in[1];
    const float* e  = (const float*)d_in[2];
    const float* W1 = (const float*)d_in[3];
    const float* b1 = (const float*)d_in[4];
    const float* W2 = (const float*)d_in[5];
    const float* b2 = (const float*)d_in[6];
    const float* W3 = (const float*)d_in[7];
    const float* b3 = (const float*)d_in[8];
    const float* W4 = (const float*)d_in[9];
    const float* b4 = (const float*)d_in[10];
    const float* cb = (const float*)d_in[11];
    float* out = (float*)d_out;

    u32*   keys    = (u32*)d_ws;                 // 8192 u32
    float* ws_loss = (float*)d_ws + 8192;        // 64 f32

    k0_init<<<32, 256, 0, stream>>>(keys);
    k1_pointfeat<<<1024, 256, 0, stream>>>(x, s, W1, b1, W2, keys);
    k2_head<<<64, 512, 0, stream>>>(keys, b2, e, W3, b3, W4, b4, cb, out, ws_loss);
    k3_loss<<<1, 64, 0, stream>>>(ws_loss, out);
}

// Round 5
// 62.101 us; speedup vs baseline: 1.4317x; 1.4317x over previous
//
#include <hip/hip_runtime.h>

typedef unsigned int u32;
typedef __attribute__((ext_vector_type(4))) unsigned int u32x4;
typedef __attribute__((ext_vector_type(8))) short s16x8;
typedef __attribute__((ext_vector_type(16))) float f32x16;
typedef __attribute__((ext_vector_type(4))) float f32x4;

__device__ __forceinline__ u32 mono(float f) {
    u32 u = __float_as_uint(f);
    return (u & 0x80000000u) ? ~u : (u | 0x80000000u);
}
__device__ __forceinline__ float unmono(u32 k) {
    return __uint_as_float((k & 0x80000000u) ? (k & 0x7fffffffu) : ~k);
}
// bf16 RNE of a, returned as f32 bit pattern (low 16 cleared)
__device__ __forceinline__ u32 rne_hi(float a) {
    u32 u = __float_as_uint(a);
    return (u + 0x7FFFu + ((u >> 16) & 1u)) & 0xFFFF0000u;
}

__global__ void k0_init(u32* __restrict__ keys) {
    int idx = blockIdx.x * 256 + threadIdx.x;
    if (idx < 8192) keys[idx] = 0u;   // mono-space -inf
}

// Cooperative split-bf16 MFMA point-feature kernel (unchanged from round 4).
__global__ __launch_bounds__(256, 4) void k1_pointfeat(
    const float* __restrict__ x, const float* __restrict__ s,
    const float* __restrict__ W1, const float* __restrict__ b1,
    const float* __restrict__ W2, u32* __restrict__ keys)
{
    __shared__ __align__(16) u32 Hlds[2 * 2 * 64 * 36];
    const int tid   = threadIdx.x;
    const int lane  = tid & 63;
    const int point = tid & 63;
    const int kq    = __builtin_amdgcn_readfirstlane(tid >> 6);
    const int cl    = lane & 31;
    const int kg    = lane >> 5;
    const int mrow  = (kq >> 1) * 32;
    const int ntp   = (kq & 1) * 2;

    const int p0 = blockIdx.x * 512;
    const int b  = blockIdx.x >> 4;

    s16x8 wh[2][4], wl[2][4];
    #pragma unroll
    for (int p = 0; p < 2; ++p)
        #pragma unroll
        for (int sl = 0; sl < 4; ++sl)
            #pragma unroll
            for (int j = 0; j < 8; ++j) {
                float f = W2[(sl * 16 + kg * 8 + j) * 128 + (ntp + p) * 32 + cl];
                u32 hb = rne_hi(f);
                float lo = f - __uint_as_float(hb);
                u32 lb = rne_hi(lo);
                wh[p][sl][j] = (short)(hb >> 16);
                wl[p][sl][j] = (short)(lb >> 16);
            }

    float rmax0 = -3.402823466e38f, rmax1 = -3.402823466e38f;

    float px, py, pz, pw;
    {
        const int gp = p0 + point;
        px = x[(size_t)gp * 3 + 0]; py = x[(size_t)gp * 3 + 1];
        pz = x[(size_t)gp * 3 + 2]; pw = s[gp];
    }

    #pragma unroll 2
    for (int g = 0; g < 8; ++g) {
        {
            u32 hp[8], lp[8];
            #pragma unroll
            for (int c = 0; c < 8; ++c) {
                const int k0 = kq * 16 + c * 2;
                float a0 = fmaf(px, W1[k0],
                           fmaf(py, W1[64 + k0],
                           fmaf(pz, W1[128 + k0],
                           fmaf(pw, W1[192 + k0], b1[k0]))));
                float a1 = fmaf(px, W1[k0 + 1],
                           fmaf(py, W1[65 + k0],
                           fmaf(pz, W1[129 + k0],
                           fmaf(pw, W1[193 + k0], b1[k0 + 1]))));
                a0 = a0 > 0.f ? a0 : 0.f;
                a1 = a1 > 0.f ? a1 : 0.f;
                u32 h0 = rne_hi(a0), h1 = rne_hi(a1);
                float l0 = a0 - __uint_as_float(h0);
                float l1 = a1 - __uint_as_float(h1);
                hp[c] = __builtin_amdgcn_perm(h1, h0, 0x07060302u);
                lp[c] = __builtin_amdgcn_perm(__float_as_uint(l1),
                                              __float_as_uint(l0), 0x07060302u);
            }
            u32* Hw = &Hlds[(g & 1) * 4608 + point * 36 + kq * 8];
            u32x4 v0 = {hp[0], hp[1], hp[2], hp[3]};
            u32x4 v1 = {hp[4], hp[5], hp[6], hp[7]};
            u32x4 v2 = {lp[0], lp[1], lp[2], lp[3]};
            u32x4 v3 = {lp[4], lp[5], lp[6], lp[7]};
            *(u32x4*)(Hw)            = v0;
            *(u32x4*)(Hw + 4)        = v1;
            *(u32x4*)(Hw + 2304)     = v2;
            *(u32x4*)(Hw + 2304 + 4) = v3;
        }
        __syncthreads();
        if (g < 7) {
            const int gp = p0 + (g + 1) * 64 + point;
            px = x[(size_t)gp * 3 + 0]; py = x[(size_t)gp * 3 + 1];
            pz = x[(size_t)gp * 3 + 2]; pw = s[gp];
        }
        const u32* Hb = &Hlds[(g & 1) * 4608];
        f32x16 acc0 = {}, acc1 = {};
        __builtin_amdgcn_s_setprio(1);
        #pragma unroll
        for (int sl = 0; sl < 4; ++sl) {
            s16x8 ahi = *(const s16x8*)(Hb + (mrow + cl) * 36 + sl * 8 + kg * 4);
            s16x8 alo = *(const s16x8*)(Hb + 2304 + (mrow + cl) * 36 + sl * 8 + kg * 4);
            acc0 = __builtin_amdgcn_mfma_f32_32x32x16_bf16(ahi, wh[0][sl], acc0, 0, 0, 0);
            acc1 = __builtin_amdgcn_mfma_f32_32x32x16_bf16(ahi, wh[1][sl], acc1, 0, 0, 0);
            acc0 = __builtin_amdgcn_mfma_f32_32x32x16_bf16(ahi, wl[0][sl], acc0, 0, 0, 0);
            acc1 = __builtin_amdgcn_mfma_f32_32x32x16_bf16(ahi, wl[1][sl], acc1, 0, 0, 0);
            acc0 = __builtin_amdgcn_mfma_f32_32x32x16_bf16(alo, wh[0][sl], acc0, 0, 0, 0);
            acc1 = __builtin_amdgcn_mfma_f32_32x32x16_bf16(alo, wh[1][sl], acc1, 0, 0, 0);
        }
        __builtin_amdgcn_s_setprio(0);
        #pragma unroll
        for (int r = 0; r < 16; ++r) {
            rmax0 = fmaxf(rmax0, acc0[r]);
            rmax1 = fmaxf(rmax1, acc1[r]);
        }
    }

    rmax0 = fmaxf(rmax0, __shfl_xor(rmax0, 32, 64));
    rmax1 = fmaxf(rmax1, __shfl_xor(rmax1, 32, 64));
    if (lane < 32) {
        atomicMax(&keys[b * 128 + (ntp + 0) * 32 + cl], mono(rmax0));
        atomicMax(&keys[b * 128 + (ntp + 1) * 32 + cl], mono(rmax1));
    }
}

// Hidden layer: block = (batch, 64-unit chunk); thread = (unit, i-quarter).
// No unroll pragmas — compiler picks (round-3 lesson: hand-capping unroll
// strangles MLP on latency-bound loops).
__global__ __launch_bounds__(256) void k2a_hidden(
    const u32* __restrict__ keys, const float* __restrict__ b2,
    const float* __restrict__ e,
    const float* __restrict__ W3, const float* __restrict__ b3,
    float* __restrict__ ws_hid)
{
    const int blk = blockIdx.x;        // 256 = 64 batches x 4 chunks
    const int b   = blk >> 2;
    const int c   = blk & 3;
    const int tid = threadIdx.x;
    const int u   = tid & 63;
    const int part = tid >> 6;         // 0..3, i-range quarter
    __shared__ float comb[640];
    __shared__ float psum[4][64];

    for (int i = tid; i < 640; i += 256)
        comb[i] = (i < 128) ? unmono(keys[b * 128 + i]) + b2[i]
                            : e[b * 512 + (i - 128)];
    __syncthreads();

    const int gu = c * 64 + u;
    const float* __restrict__ Wp = W3 + (size_t)(part * 160) * 256 + gu;
    const float* __restrict__ cp = comb + part * 160;
    float a = 0.f;
    for (int i = 0; i < 160; ++i) a = fmaf(cp[i], Wp[(size_t)i * 256], a);
    psum[part][u] = a;
    __syncthreads();
    if (tid < 64) {
        float hv = psum[0][u] + psum[1][u] + psum[2][u] + psum[3][u] + b3[gu];
        ws_hid[b * 256 + gu] = hv > 0.f ? hv : 0.f;
    }
}

// z_e + VQ + per-batch loss partial. 64 blocks x 512 threads.
__global__ __launch_bounds__(512) void k2b_vq(
    const float* __restrict__ ws_hid,
    const float* __restrict__ W4, const float* __restrict__ b4,
    const float* __restrict__ cb, float* __restrict__ out,
    float* __restrict__ ws_loss)
{
    const int b = blockIdx.x, tid = threadIdx.x;
    __shared__ float hid[256];
    __shared__ float psum[4][128];
    __shared__ float ze[128];
    __shared__ float red_d[512];
    __shared__ int   red_i[512];
    __shared__ float lred[128];
    __shared__ float zzs;

    if (tid < 256) hid[tid] = ws_hid[b * 256 + tid];
    __syncthreads();

    // z_e partials: unit u = tid&127, i-quarter = tid>>7 (4 x 64)
    {
        const int u = tid & 127, part = tid >> 7;
        const float* __restrict__ Wp = W4 + (size_t)(part * 64) * 128 + u;
        const float* __restrict__ hp = hid + part * 64;
        float a = 0.f;
        for (int i = 0; i < 64; ++i) a = fmaf(hp[i], Wp[(size_t)i * 128], a);
        psum[part][u] = a;
    }
    __syncthreads();
    if (tid < 128) {
        float a = psum[0][tid] + psum[1][tid] + psum[2][tid] + psum[3][tid] + b4[tid];
        ze[tid] = a;
        out[8192 + b * 128 + tid] = a;     // z_e
    }
    __syncthreads();

    if (tid < 64) {
        float t = ze[tid] * ze[tid] + ze[tid + 64] * ze[tid + 64];
        #pragma unroll
        for (int d = 1; d < 64; d <<= 1) t += __shfl_xor(t, d, 64);
        if (tid == 0) zzs = t;
    }
    __syncthreads();

    // dists: one code per thread, float4 codebook loads
    {
        float dot = 0.f, cc = 0.f;
        const f32x4* __restrict__ cp = (const f32x4*)(cb + (size_t)tid * 128);
        for (int k4 = 0; k4 < 32; ++k4) {
            f32x4 v = cp[k4];
            dot = fmaf(ze[k4 * 4 + 0], v.x, dot);
            cc  = fmaf(v.x, v.x, cc);
            dot = fmaf(ze[k4 * 4 + 1], v.y, dot);
            cc  = fmaf(v.y, v.y, cc);
            dot = fmaf(ze[k4 * 4 + 2], v.z, dot);
            cc  = fmaf(v.z, v.z, cc);
            dot = fmaf(ze[k4 * 4 + 3], v.w, dot);
            cc  = fmaf(v.w, v.w, cc);
        }
        red_d[tid] = zzs - 2.f * dot + cc;
        red_i[tid] = tid;
    }
    __syncthreads();

    // argmin (tie -> lowest index, = np.argmin)
    for (int sft = 256; sft >= 1; sft >>= 1) {
        if (tid < sft) {
            float da = red_d[tid], db = red_d[tid + sft];
            int   ia = red_i[tid], ib = red_i[tid + sft];
            if (db < da || (db == da && ib < ia)) { red_d[tid] = db; red_i[tid] = ib; }
        }
        __syncthreads();
    }
    const int bc = red_i[0];

    if (tid < 128) {
        float zq  = cb[(size_t)bc * 128 + tid];
        float zev = ze[tid];
        out[b * 128 + tid] = zev + (zq - zev);   // z_q_st
        float d = zq - zev;
        lred[tid] = d * d;
    }
    if (tid == 0) out[16386 + b] = (float)bc;
    __syncthreads();
    if (tid < 64) {
        float t = lred[tid] + lred[tid + 64];
        #pragma unroll
        for (int d = 1; d < 64; d <<= 1) t += __shfl_xor(t, d, 64);
        if (tid == 0) ws_loss[b] = t;
    }
}

// Single-wave loss finalize.
__global__ void k3_loss(const float* __restrict__ ws_loss, float* __restrict__ out)
{
    const int t = threadIdx.x;   // 64 threads
    float v = ws_loss[t];
    #pragma unroll
    for (int d = 1; d < 64; d <<= 1) v += __shfl_xor(v, d, 64);
    if (t == 0) {
        float m = v / 8192.f;
        out[16384] = m;   // codebook_loss
        out[16385] = m;   // commitment_loss (numerically identical)
    }
}

extern "C" void kernel_launch(void* const* d_in, const int* in_sizes, int n_in,
                              void* d_out, int out_size, void* d_ws, size_t ws_size,
                              hipStream_t stream) {
    const float* x  = (const float*)d_in[0];
    const float* s  = (const float*)d_in[1];
    const float* e  = (const float*)d_in[2];
    const float* W1 = (const float*)d_in[3];
    const float* b1 = (const float*)d_in[4];
    const float* W2 = (const float*)d_in[5];
    const float* b2 = (const float*)d_in[6];
    const float* W3 = (const float*)d_in[7];
    const float* b3 = (const float*)d_in[8];
    const float* W4 = (const float*)d_in[9];
    const float* b4 = (const float*)d_in[10];
    const float* cb = (const float*)d_in[11];
    float* out = (float*)d_out;

    u32*   keys    = (u32*)d_ws;                 // 8192 u32 = 32 KB
    float* ws_loss = (float*)d_ws + 8192;        // 64 f32
    float* ws_hid  = (float*)d_ws + 8192 + 64;   // 64*256 f32 = 64 KB

    k0_init<<<32, 256, 0, stream>>>(keys);
    k1_pointfeat<<<1024, 256, 0, stream>>>(x, s, W1, b1, W2, keys);
    k2a_hidden<<<256, 256, 0, stream>>>(keys, b2, e, W3, b3, ws_hid);
    k2b_vq<<<64, 512, 0, stream>>>(ws_hid, W4, b4, cb, out, ws_loss);
    k3_loss<<<1, 64, 0, stream>>>(ws_loss, out);
}

// Round 6
// 57.910 us; speedup vs baseline: 1.5353x; 1.0724x over previous
//
#include <hip/hip_runtime.h>

typedef unsigned int u32;
typedef __attribute__((ext_vector_type(4))) unsigned int u32x4;
typedef __attribute__((ext_vector_type(8))) short s16x8;
typedef __attribute__((ext_vector_type(16))) float f32x16;
typedef __attribute__((ext_vector_type(4))) float f32x4;

__device__ __forceinline__ u32 mono(float f) {
    u32 u = __float_as_uint(f);
    return (u & 0x80000000u) ? ~u : (u | 0x80000000u);
}
__device__ __forceinline__ float unmono(u32 k) {
    return __uint_as_float((k & 0x80000000u) ? (k & 0x7fffffffu) : ~k);
}
// bf16 RNE of a, returned as f32 bit pattern (low 16 cleared)
__device__ __forceinline__ u32 rne_hi(float a) {
    u32 u = __float_as_uint(a);
    return (u + 0x7FFFu + ((u >> 16) & 1u)) & 0xFFFF0000u;
}

__global__ void k0_init(u32* __restrict__ keys) {
    int idx = blockIdx.x * 256 + threadIdx.x;
    if (idx < 8192) keys[idx] = 0u;   // mono-space -inf
}

// Cooperative split-bf16 MFMA point-feature kernel.
// Round-6 changes vs round 5 (all aimed at fitting the 128-reg budget of
// 4 waves/SIMD, which round 5 missed by ~8 regs -> 20 MB scratch traffic):
//  - stage split/pack interleaved with LDS writes (hp/lp 16 -> 8 regs)
//  - no next-group coord prefetch (8 -> 4 regs)
//  - unroll 1 on the group loop (no cross-group live ranges)
__global__ __launch_bounds__(256, 4) void k1_pointfeat(
    const float* __restrict__ x, const float* __restrict__ s,
    const float* __restrict__ W1, const float* __restrict__ b1,
    const float* __restrict__ W2, u32* __restrict__ keys)
{
    __shared__ __align__(16) u32 Hlds[2 * 2 * 64 * 36];
    const int tid   = threadIdx.x;
    const int lane  = tid & 63;
    const int point = tid & 63;
    const int kq    = __builtin_amdgcn_readfirstlane(tid >> 6);
    const int cl    = lane & 31;
    const int kg    = lane >> 5;
    const int mrow  = (kq >> 1) * 32;
    const int ntp   = (kq & 1) * 2;

    const int p0 = blockIdx.x * 512;
    const int b  = blockIdx.x >> 4;

    // W2 split fragments for this wave's two nt tiles (resident, 64 regs)
    s16x8 wh[2][4], wl[2][4];
    #pragma unroll
    for (int p = 0; p < 2; ++p)
        #pragma unroll
        for (int sl = 0; sl < 4; ++sl)
            #pragma unroll
            for (int j = 0; j < 8; ++j) {
                float f = W2[(sl * 16 + kg * 8 + j) * 128 + (ntp + p) * 32 + cl];
                u32 hb = rne_hi(f);
                float lo = f - __uint_as_float(hb);
                u32 lb = rne_hi(lo);
                wh[p][sl][j] = (short)(hb >> 16);
                wl[p][sl][j] = (short)(lb >> 16);
            }

    float rmax0 = -3.402823466e38f, rmax1 = -3.402823466e38f;

    #pragma unroll 1
    for (int g = 0; g < 8; ++g) {
        // ---- stage group g into buf (g&1) ----
        {
            const int gp = p0 + g * 64 + point;
            const float px = x[(size_t)gp * 3 + 0];
            const float py = x[(size_t)gp * 3 + 1];
            const float pz = x[(size_t)gp * 3 + 2];
            const float pw = s[gp];
            u32* Hw = &Hlds[(g & 1) * 4608 + point * 36 + kq * 8];
            #pragma unroll
            for (int h = 0; h < 2; ++h) {
                u32 hp[4], lp[4];
                #pragma unroll
                for (int c = 0; c < 4; ++c) {
                    const int k0 = kq * 16 + h * 8 + c * 2;
                    float a0 = fmaf(px, W1[k0],
                               fmaf(py, W1[64 + k0],
                               fmaf(pz, W1[128 + k0],
                               fmaf(pw, W1[192 + k0], b1[k0]))));
                    float a1 = fmaf(px, W1[k0 + 1],
                               fmaf(py, W1[65 + k0],
                               fmaf(pz, W1[129 + k0],
                               fmaf(pw, W1[193 + k0], b1[k0 + 1]))));
                    a0 = a0 > 0.f ? a0 : 0.f;
                    a1 = a1 > 0.f ? a1 : 0.f;
                    u32 h0 = rne_hi(a0), h1 = rne_hi(a1);
                    float l0 = a0 - __uint_as_float(h0);
                    float l1 = a1 - __uint_as_float(h1);
                    hp[c] = __builtin_amdgcn_perm(h1, h0, 0x07060302u);
                    lp[c] = __builtin_amdgcn_perm(__float_as_uint(l1),
                                                  __float_as_uint(l0), 0x07060302u);
                }
                u32x4 vh = {hp[0], hp[1], hp[2], hp[3]};
                u32x4 vl = {lp[0], lp[1], lp[2], lp[3]};
                *(u32x4*)(Hw + h * 4)        = vh;
                *(u32x4*)(Hw + 2304 + h * 4) = vl;
            }
        }
        __syncthreads();
        // ---- compute group g from buf (g&1) ----
        const u32* Hb = &Hlds[(g & 1) * 4608];
        f32x16 acc0 = {}, acc1 = {};
        __builtin_amdgcn_s_setprio(1);
        #pragma unroll
        for (int sl = 0; sl < 4; ++sl) {
            s16x8 ahi = *(const s16x8*)(Hb + (mrow + cl) * 36 + sl * 8 + kg * 4);
            s16x8 alo = *(const s16x8*)(Hb + 2304 + (mrow + cl) * 36 + sl * 8 + kg * 4);
            acc0 = __builtin_amdgcn_mfma_f32_32x32x16_bf16(ahi, wh[0][sl], acc0, 0, 0, 0);
            acc1 = __builtin_amdgcn_mfma_f32_32x32x16_bf16(ahi, wh[1][sl], acc1, 0, 0, 0);
            acc0 = __builtin_amdgcn_mfma_f32_32x32x16_bf16(ahi, wl[0][sl], acc0, 0, 0, 0);
            acc1 = __builtin_amdgcn_mfma_f32_32x32x16_bf16(ahi, wl[1][sl], acc1, 0, 0, 0);
            acc0 = __builtin_amdgcn_mfma_f32_32x32x16_bf16(alo, wh[0][sl], acc0, 0, 0, 0);
            acc1 = __builtin_amdgcn_mfma_f32_32x32x16_bf16(alo, wh[1][sl], acc1, 0, 0, 0);
        }
        __builtin_amdgcn_s_setprio(0);
        #pragma unroll
        for (int r = 0; r < 16; ++r) {
            rmax0 = fmaxf(rmax0, acc0[r]);
            rmax1 = fmaxf(rmax1, acc1[r]);
        }
        // no trailing sync: next iter writes the OTHER buffer; reads of that
        // buffer finished before this iter's barrier (lgkmcnt drains at sync).
    }

    rmax0 = fmaxf(rmax0, __shfl_xor(rmax0, 32, 64));
    rmax1 = fmaxf(rmax1, __shfl_xor(rmax1, 32, 64));
    if (lane < 32) {
        atomicMax(&keys[b * 128 + (ntp + 0) * 32 + cl], mono(rmax0));
        atomicMax(&keys[b * 128 + (ntp + 1) * 32 + cl], mono(rmax1));
    }
}

// Hidden layer: block = (batch, 64-unit chunk); thread = (unit, i-quarter).
__global__ __launch_bounds__(256) void k2a_hidden(
    const u32* __restrict__ keys, const float* __restrict__ b2,
    const float* __restrict__ e,
    const float* __restrict__ W3, const float* __restrict__ b3,
    float* __restrict__ ws_hid)
{
    const int blk = blockIdx.x;        // 256 = 64 batches x 4 chunks
    const int b   = blk >> 2;
    const int c   = blk & 3;
    const int tid = threadIdx.x;
    const int u   = tid & 63;
    const int part = tid >> 6;         // 0..3, i-range quarter
    __shared__ float comb[640];
    __shared__ float psum[4][64];

    for (int i = tid; i < 640; i += 256)
        comb[i] = (i < 128) ? unmono(keys[b * 128 + i]) + b2[i]
                            : e[b * 512 + (i - 128)];
    __syncthreads();

    const int gu = c * 64 + u;
    const float* __restrict__ Wp = W3 + (size_t)(part * 160) * 256 + gu;
    const float* __restrict__ cp = comb + part * 160;
    float a = 0.f;
    for (int i = 0; i < 160; ++i) a = fmaf(cp[i], Wp[(size_t)i * 256], a);
    psum[part][u] = a;
    __syncthreads();
    if (tid < 64) {
        float hv = psum[0][u] + psum[1][u] + psum[2][u] + psum[3][u] + b3[gu];
        ws_hid[b * 256 + gu] = hv > 0.f ? hv : 0.f;
    }
}

// z_e + VQ + per-batch loss partial. 64 blocks x 512 threads.
__global__ __launch_bounds__(512) void k2b_vq(
    const float* __restrict__ ws_hid,
    const float* __restrict__ W4, const float* __restrict__ b4,
    const float* __restrict__ cb, float* __restrict__ out,
    float* __restrict__ ws_loss)
{
    const int b = blockIdx.x, tid = threadIdx.x;
    __shared__ float hid[256];
    __shared__ float psum[4][128];
    __shared__ float ze[128];
    __shared__ float red_d[512];
    __shared__ int   red_i[512];
    __shared__ float lred[128];
    __shared__ float zzs;

    if (tid < 256) hid[tid] = ws_hid[b * 256 + tid];
    __syncthreads();

    {
        const int u = tid & 127, part = tid >> 7;
        const float* __restrict__ Wp = W4 + (size_t)(part * 64) * 128 + u;
        const float* __restrict__ hp = hid + part * 64;
        float a = 0.f;
        for (int i = 0; i < 64; ++i) a = fmaf(hp[i], Wp[(size_t)i * 128], a);
        psum[part][u] = a;
    }
    __syncthreads();
    if (tid < 128) {
        float a = psum[0][tid] + psum[1][tid] + psum[2][tid] + psum[3][tid] + b4[tid];
        ze[tid] = a;
        out[8192 + b * 128 + tid] = a;     // z_e
    }
    __syncthreads();

    if (tid < 64) {
        float t = ze[tid] * ze[tid] + ze[tid + 64] * ze[tid + 64];
        #pragma unroll
        for (int d = 1; d < 64; d <<= 1) t += __shfl_xor(t, d, 64);
        if (tid == 0) zzs = t;
    }
    __syncthreads();

    {
        float dot = 0.f, cc = 0.f;
        const f32x4* __restrict__ cp = (const f32x4*)(cb + (size_t)tid * 128);
        for (int k4 = 0; k4 < 32; ++k4) {
            f32x4 v = cp[k4];
            dot = fmaf(ze[k4 * 4 + 0], v.x, dot);
            cc  = fmaf(v.x, v.x, cc);
            dot = fmaf(ze[k4 * 4 + 1], v.y, dot);
            cc  = fmaf(v.y, v.y, cc);
            dot = fmaf(ze[k4 * 4 + 2], v.z, dot);
            cc  = fmaf(v.z, v.z, cc);
            dot = fmaf(ze[k4 * 4 + 3], v.w, dot);
            cc  = fmaf(v.w, v.w, cc);
        }
        red_d[tid] = zzs - 2.f * dot + cc;
        red_i[tid] = tid;
    }
    __syncthreads();

    for (int sft = 256; sft >= 1; sft >>= 1) {
        if (tid < sft) {
            float da = red_d[tid], db = red_d[tid + sft];
            int   ia = red_i[tid], ib = red_i[tid + sft];
            if (db < da || (db == da && ib < ia)) { red_d[tid] = db; red_i[tid] = ib; }
        }
        __syncthreads();
    }
    const int bc = red_i[0];

    if (tid < 128) {
        float zq  = cb[(size_t)bc * 128 + tid];
        float zev = ze[tid];
        out[b * 128 + tid] = zev + (zq - zev);   // z_q_st
        float d = zq - zev;
        lred[tid] = d * d;
    }
    if (tid == 0) out[16386 + b] = (float)bc;
    __syncthreads();
    if (tid < 64) {
        float t = lred[tid] + lred[tid + 64];
        #pragma unroll
        for (int d = 1; d < 64; d <<= 1) t += __shfl_xor(t, d, 64);
        if (tid == 0) ws_loss[b] = t;
    }
}

// Single-wave loss finalize.
__global__ void k3_loss(const float* __restrict__ ws_loss, float* __restrict__ out)
{
    const int t = threadIdx.x;   // 64 threads
    float v = ws_loss[t];
    #pragma unroll
    for (int d = 1; d < 64; d <<= 1) v += __shfl_xor(v, d, 64);
    if (t == 0) {
        float m = v / 8192.f;
        out[16384] = m;   // codebook_loss
        out[16385] = m;   // commitment_loss (numerically identical)
    }
}

extern "C" void kernel_launch(void* const* d_in, const int* in_sizes, int n_in,
                              void* d_out, int out_size, void* d_ws, size_t ws_size,
                              hipStream_t stream) {
    const float* x  = (const float*)d_in[0];
    const float* s  = (const float*)d_in[1];
    const float* e  = (const float*)d_in[2];
    const float* W1 = (const float*)d_in[3];
    const float* b1 = (const float*)d_in[4];
    const float* W2 = (const float*)d_in[5];
    const float* b2 = (const float*)d_in[6];
    const float* W3 = (const float*)d_in[7];
    const float* b3 = (const float*)d_in[8];
    const float* W4 = (const float*)d_in[9];
    const float* b4 = (const float*)d_in[10];
    const float* cb = (const float*)d_in[11];
    float* out = (float*)d_out;

    u32*   keys    = (u32*)d_ws;                 // 8192 u32 = 32 KB
    float* ws_loss = (float*)d_ws + 8192;        // 64 f32
    float* ws_hid  = (float*)d_ws + 8192 + 64;   // 64*256 f32 = 64 KB

    k0_init<<<32, 256, 0, stream>>>(keys);
    k1_pointfeat<<<1024, 256, 0, stream>>>(x, s, W1, b1, W2, keys);
    k2a_hidden<<<256, 256, 0, stream>>>(keys, b2, e, W3, b3, ws_hid);
    k2b_vq<<<64, 512, 0, stream>>>(ws_hid, W4, b4, cb, out, ws_loss);
    k3_loss<<<1, 64, 0, stream>>>(ws_loss, out);
}

// Round 7
// 54.288 us; speedup vs baseline: 1.6377x; 1.0667x over previous
//
#include <hip/hip_runtime.h>

typedef unsigned int u32;
typedef __attribute__((ext_vector_type(4))) unsigned int u32x4;
typedef __attribute__((ext_vector_type(8))) short s16x8;
typedef __attribute__((ext_vector_type(16))) float f32x16;
typedef __attribute__((ext_vector_type(4))) float f32x4;

__device__ __forceinline__ u32 mono(float f) {
    u32 u = __float_as_uint(f);
    return (u & 0x80000000u) ? ~u : (u | 0x80000000u);
}
__device__ __forceinline__ float unmono(u32 k) {
    return __uint_as_float((k & 0x80000000u) ? (k & 0x7fffffffu) : ~k);
}
// bf16 RNE of a, returned as f32 bit pattern (low 16 cleared)
__device__ __forceinline__ u32 rne_hi(float a) {
    u32 u = __float_as_uint(a);
    return (u + 0x7FFFu + ((u >> 16) & 1u)) & 0xFFFF0000u;
}

__global__ void k0_init(u32* __restrict__ keys) {
    int idx = blockIdx.x * 256 + threadIdx.x;
    if (idx < 8192) keys[idx] = 0u;   // mono-space -inf
}

// Cooperative split-bf16 MFMA point-feature kernel.
// Round-7 repartition: wave = ONE nt tile (wh/wl 32 regs, was 64), loops both
// m tiles re-reading A frags from LDS (ds_read_b128 ~12cyc, cheap). Static
// reg demand ~92 <= 128 budget of 4 waves/SIMD -> no spill (rounds 5/6
// spilled 11-20 MB because W2 residency pushed VGPR-side demand past the
// allocator's 64/64 V/A split).
__global__ __launch_bounds__(256, 4) void k1_pointfeat(
    const float* __restrict__ x, const float* __restrict__ s,
    const float* __restrict__ W1, const float* __restrict__ b1,
    const float* __restrict__ W2, u32* __restrict__ keys)
{
    __shared__ __align__(16) u32 Hlds[2 * 2 * 64 * 36];
    const int tid   = threadIdx.x;
    const int lane  = tid & 63;
    const int point = tid & 63;
    const int kq    = __builtin_amdgcn_readfirstlane(tid >> 6); // wave = nt tile
    const int cl    = lane & 31;
    const int kg    = lane >> 5;

    const int p0 = blockIdx.x * 512;
    const int b  = blockIdx.x >> 4;

    // W2 split fragments for nt = kq (resident, 32 regs)
    s16x8 wh[4], wl[4];
    #pragma unroll
    for (int sl = 0; sl < 4; ++sl)
        #pragma unroll
        for (int j = 0; j < 8; ++j) {
            float f = W2[(sl * 16 + kg * 8 + j) * 128 + kq * 32 + cl];
            u32 hb = rne_hi(f);
            float lo = f - __uint_as_float(hb);
            u32 lb = rne_hi(lo);
            wh[sl][j] = (short)(hb >> 16);
            wl[sl][j] = (short)(lb >> 16);
        }

    float rmax = -3.402823466e38f;

    #pragma unroll 1
    for (int g = 0; g < 8; ++g) {
        // ---- stage group g into buf (g&1) ----
        {
            const int gp = p0 + g * 64 + point;
            const float px = x[(size_t)gp * 3 + 0];
            const float py = x[(size_t)gp * 3 + 1];
            const float pz = x[(size_t)gp * 3 + 2];
            const float pw = s[gp];
            u32* Hw = &Hlds[(g & 1) * 4608 + point * 36 + kq * 8];
            #pragma unroll
            for (int h = 0; h < 2; ++h) {
                u32 hp[4], lp[4];
                #pragma unroll
                for (int c = 0; c < 4; ++c) {
                    const int k0 = kq * 16 + h * 8 + c * 2;
                    float a0 = fmaf(px, W1[k0],
                               fmaf(py, W1[64 + k0],
                               fmaf(pz, W1[128 + k0],
                               fmaf(pw, W1[192 + k0], b1[k0]))));
                    float a1 = fmaf(px, W1[k0 + 1],
                               fmaf(py, W1[65 + k0],
                               fmaf(pz, W1[129 + k0],
                               fmaf(pw, W1[193 + k0], b1[k0 + 1]))));
                    a0 = a0 > 0.f ? a0 : 0.f;
                    a1 = a1 > 0.f ? a1 : 0.f;
                    u32 h0 = rne_hi(a0), h1 = rne_hi(a1);
                    float l0 = a0 - __uint_as_float(h0);
                    float l1 = a1 - __uint_as_float(h1);
                    hp[c] = __builtin_amdgcn_perm(h1, h0, 0x07060302u);
                    lp[c] = __builtin_amdgcn_perm(__float_as_uint(l1),
                                                  __float_as_uint(l0), 0x07060302u);
                }
                u32x4 vh = {hp[0], hp[1], hp[2], hp[3]};
                u32x4 vl = {lp[0], lp[1], lp[2], lp[3]};
                *(u32x4*)(Hw + h * 4)        = vh;
                *(u32x4*)(Hw + 2304 + h * 4) = vl;
            }
        }
        __syncthreads();
        // ---- compute group g from buf (g&1): both m tiles, nt = kq ----
        const u32* Hb = &Hlds[(g & 1) * 4608];
        f32x16 acc0 = {}, acc1 = {};
        __builtin_amdgcn_s_setprio(1);
        #pragma unroll
        for (int sl = 0; sl < 4; ++sl) {
            s16x8 ahi0 = *(const s16x8*)(Hb + cl * 36 + sl * 8 + kg * 4);
            s16x8 alo0 = *(const s16x8*)(Hb + 2304 + cl * 36 + sl * 8 + kg * 4);
            acc0 = __builtin_amdgcn_mfma_f32_32x32x16_bf16(ahi0, wh[sl], acc0, 0, 0, 0);
            acc0 = __builtin_amdgcn_mfma_f32_32x32x16_bf16(ahi0, wl[sl], acc0, 0, 0, 0);
            acc0 = __builtin_amdgcn_mfma_f32_32x32x16_bf16(alo0, wh[sl], acc0, 0, 0, 0);
            s16x8 ahi1 = *(const s16x8*)(Hb + (32 + cl) * 36 + sl * 8 + kg * 4);
            s16x8 alo1 = *(const s16x8*)(Hb + 2304 + (32 + cl) * 36 + sl * 8 + kg * 4);
            acc1 = __builtin_amdgcn_mfma_f32_32x32x16_bf16(ahi1, wh[sl], acc1, 0, 0, 0);
            acc1 = __builtin_amdgcn_mfma_f32_32x32x16_bf16(ahi1, wl[sl], acc1, 0, 0, 0);
            acc1 = __builtin_amdgcn_mfma_f32_32x32x16_bf16(alo1, wh[sl], acc1, 0, 0, 0);
        }
        __builtin_amdgcn_s_setprio(0);
        #pragma unroll
        for (int r = 0; r < 16; ++r)
            rmax = fmaxf(rmax, fmaxf(acc0[r], acc1[r]));
        // no trailing sync: next iter writes the OTHER buffer; this buffer's
        // reads completed before the next barrier's lgkmcnt drain.
    }

    rmax = fmaxf(rmax, __shfl_xor(rmax, 32, 64));
    if (lane < 32)
        atomicMax(&keys[b * 128 + kq * 32 + cl], mono(rmax));
}

// Hidden layer: block = (batch, 64-unit chunk); thread = (unit, i-quarter).
__global__ __launch_bounds__(256) void k2a_hidden(
    const u32* __restrict__ keys, const float* __restrict__ b2,
    const float* __restrict__ e,
    const float* __restrict__ W3, const float* __restrict__ b3,
    float* __restrict__ ws_hid)
{
    const int blk = blockIdx.x;        // 256 = 64 batches x 4 chunks
    const int b   = blk >> 2;
    const int c   = blk & 3;
    const int tid = threadIdx.x;
    const int u   = tid & 63;
    const int part = tid >> 6;         // 0..3, i-range quarter
    __shared__ float comb[640];
    __shared__ float psum[4][64];

    for (int i = tid; i < 640; i += 256)
        comb[i] = (i < 128) ? unmono(keys[b * 128 + i]) + b2[i]
                            : e[b * 512 + (i - 128)];
    __syncthreads();

    const int gu = c * 64 + u;
    const float* __restrict__ Wp = W3 + (size_t)(part * 160) * 256 + gu;
    const float* __restrict__ cp = comb + part * 160;
    float a = 0.f;
    for (int i = 0; i < 160; ++i) a = fmaf(cp[i], Wp[(size_t)i * 256], a);
    psum[part][u] = a;
    __syncthreads();
    if (tid < 64) {
        float hv = psum[0][u] + psum[1][u] + psum[2][u] + psum[3][u] + b3[gu];
        ws_hid[b * 256 + gu] = hv > 0.f ? hv : 0.f;
    }
}

// z_e + VQ + per-batch loss partial. 64 blocks x 512 threads.
__global__ __launch_bounds__(512) void k2b_vq(
    const float* __restrict__ ws_hid,
    const float* __restrict__ W4, const float* __restrict__ b4,
    const float* __restrict__ cb, float* __restrict__ out,
    float* __restrict__ ws_loss)
{
    const int b = blockIdx.x, tid = threadIdx.x;
    __shared__ float hid[256];
    __shared__ float psum[4][128];
    __shared__ float ze[128];
    __shared__ float red_d[512];
    __shared__ int   red_i[512];
    __shared__ float lred[128];
    __shared__ float zzs;

    if (tid < 256) hid[tid] = ws_hid[b * 256 + tid];
    __syncthreads();

    {
        const int u = tid & 127, part = tid >> 7;
        const float* __restrict__ Wp = W4 + (size_t)(part * 64) * 128 + u;
        const float* __restrict__ hp = hid + part * 64;
        float a = 0.f;
        for (int i = 0; i < 64; ++i) a = fmaf(hp[i], Wp[(size_t)i * 128], a);
        psum[part][u] = a;
    }
    __syncthreads();
    if (tid < 128) {
        float a = psum[0][tid] + psum[1][tid] + psum[2][tid] + psum[3][tid] + b4[tid];
        ze[tid] = a;
        out[8192 + b * 128 + tid] = a;     // z_e
    }
    __syncthreads();

    if (tid < 64) {
        float t = ze[tid] * ze[tid] + ze[tid + 64] * ze[tid + 64];
        #pragma unroll
        for (int d = 1; d < 64; d <<= 1) t += __shfl_xor(t, d, 64);
        if (tid == 0) zzs = t;
    }
    __syncthreads();

    {
        float dot = 0.f, cc = 0.f;
        const f32x4* __restrict__ cp = (const f32x4*)(cb + (size_t)tid * 128);
        for (int k4 = 0; k4 < 32; ++k4) {
            f32x4 v = cp[k4];
            dot = fmaf(ze[k4 * 4 + 0], v.x, dot);
            cc  = fmaf(v.x, v.x, cc);
            dot = fmaf(ze[k4 * 4 + 1], v.y, dot);
            cc  = fmaf(v.y, v.y, cc);
            dot = fmaf(ze[k4 * 4 + 2], v.z, dot);
            cc  = fmaf(v.z, v.z, cc);
            dot = fmaf(ze[k4 * 4 + 3], v.w, dot);
            cc  = fmaf(v.w, v.w, cc);
        }
        red_d[tid] = zzs - 2.f * dot + cc;
        red_i[tid] = tid;
    }
    __syncthreads();

    for (int sft = 256; sft >= 1; sft >>= 1) {
        if (tid < sft) {
            float da = red_d[tid], db = red_d[tid + sft];
            int   ia = red_i[tid], ib = red_i[tid + sft];
            if (db < da || (db == da && ib < ia)) { red_d[tid] = db; red_i[tid] = ib; }
        }
        __syncthreads();
    }
    const int bc = red_i[0];

    if (tid < 128) {
        float zq  = cb[(size_t)bc * 128 + tid];
        float zev = ze[tid];
        out[b * 128 + tid] = zev + (zq - zev);   // z_q_st
        float d = zq - zev;
        lred[tid] = d * d;
    }
    if (tid == 0) out[16386 + b] = (float)bc;
    __syncthreads();
    if (tid < 64) {
        float t = lred[tid] + lred[tid + 64];
        #pragma unroll
        for (int d = 1; d < 64; d <<= 1) t += __shfl_xor(t, d, 64);
        if (tid == 0) ws_loss[b] = t;
    }
}

// Single-wave loss finalize.
__global__ void k3_loss(const float* __restrict__ ws_loss, float* __restrict__ out)
{
    const int t = threadIdx.x;   // 64 threads
    float v = ws_loss[t];
    #pragma unroll
    for (int d = 1; d < 64; d <<= 1) v += __shfl_xor(v, d, 64);
    if (t == 0) {
        float m = v / 8192.f;
        out[16384] = m;   // codebook_loss
        out[16385] = m;   // commitment_loss (numerically identical)
    }
}

extern "C" void kernel_launch(void* const* d_in, const int* in_sizes, int n_in,
                              void* d_out, int out_size, void* d_ws, size_t ws_size,
                              hipStream_t stream) {
    const float* x  = (const float*)d_in[0];
    const float* s  = (const float*)d_in[1];
    const float* e  = (const float*)d_in[2];
    const float* W1 = (const float*)d_in[3];
    const float* b1 = (const float*)d_in[4];
    const float* W2 = (const float*)d_in[5];
    const float* b2 = (const float*)d_in[6];
    const float* W3 = (const float*)d_in[7];
    const float* b3 = (const float*)d_in[8];
    const float* W4 = (const float*)d_in[9];
    const float* b4 = (const float*)d_in[10];
    const float* cb = (const float*)d_in[11];
    float* out = (float*)d_out;

    u32*   keys    = (u32*)d_ws;                 // 8192 u32 = 32 KB
    float* ws_loss = (float*)d_ws + 8192;        // 64 f32
    float* ws_hid  = (float*)d_ws + 8192 + 64;   // 64*256 f32 = 64 KB

    k0_init<<<32, 256, 0, stream>>>(keys);
    k1_pointfeat<<<1024, 256, 0, stream>>>(x, s, W1, b1, W2, keys);
    k2a_hidden<<<256, 256, 0, stream>>>(keys, b2, e, W3, b3, ws_hid);
    k2b_vq<<<64, 512, 0, stream>>>(ws_hid, W4, b4, cb, out, ws_loss);
    k3_loss<<<1, 64, 0, stream>>>(ws_loss, out);
}

// Round 8
// 50.990 us; speedup vs baseline: 1.7436x; 1.0647x over previous
//
#include <hip/hip_runtime.h>

typedef unsigned int u32;
typedef __attribute__((ext_vector_type(4))) unsigned int u32x4;
typedef __attribute__((ext_vector_type(8))) short s16x8;
typedef __attribute__((ext_vector_type(16))) float f32x16;
typedef __attribute__((ext_vector_type(4))) float f32x4;

// bf16 RNE of a, returned as f32 bit pattern (low 16 cleared)
__device__ __forceinline__ u32 rne_hi(float a) {
    u32 u = __float_as_uint(a);
    return (u + 0x7FFFu + ((u >> 16) & 1u)) & 0xFFFF0000u;
}

// Cooperative split-bf16 MFMA point-feature kernel, round-8 pipeline:
// per iter: barrier -> MFMA(buf[g]) -> layer1-VALU(g+1) -> LDS-write(buf[g^1])
// -> coord-load(g+2) -> rmax(g). Stage VALU + coord latency hide under the
// MFMA burst; rmax (which blocks on accs) runs last. Block-partial maxes
// stored to ws (no atomics, no init kernel).
__global__ __launch_bounds__(256, 4) void k1_pointfeat(
    const float* __restrict__ x, const float* __restrict__ s,
    const float* __restrict__ W1, const float* __restrict__ b1,
    const float* __restrict__ W2, float* __restrict__ ws_part)
{
    __shared__ __align__(16) u32 Hlds[2 * 2 * 64 * 36];
    const int tid   = threadIdx.x;
    const int lane  = tid & 63;
    const int point = tid & 63;
    const int kq    = __builtin_amdgcn_readfirstlane(tid >> 6); // wave = nt tile
    const int cl    = lane & 31;
    const int kg    = lane >> 5;

    const int p0 = blockIdx.x * 512;

    // W2 split fragments for nt = kq (resident, 32 regs)
    s16x8 wh[4], wl[4];
    #pragma unroll
    for (int sl = 0; sl < 4; ++sl)
        #pragma unroll
        for (int j = 0; j < 8; ++j) {
            float f = W2[(sl * 16 + kg * 8 + j) * 128 + kq * 32 + cl];
            u32 hb = rne_hi(f);
            float lo = f - __uint_as_float(hb);
            u32 lb = rne_hi(lo);
            wh[sl][j] = (short)(hb >> 16);
            wl[sl][j] = (short)(lb >> 16);
        }

    float rmax = -3.402823466e38f;

    // ---- stage helper expanded inline: layer1 + split + pack + LDS write ----
    // (macro to keep register use explicit)
#define STAGE_GROUP(GG, PX, PY, PZ, PW)                                        \
    {                                                                          \
        u32* Hw = &Hlds[((GG) & 1) * 4608 + point * 36 + kq * 8];              \
        _Pragma("unroll")                                                      \
        for (int h = 0; h < 2; ++h) {                                          \
            u32 hp[4], lp[4];                                                  \
            _Pragma("unroll")                                                  \
            for (int c = 0; c < 4; ++c) {                                      \
                const int k0 = kq * 16 + h * 8 + c * 2;                        \
                float a0 = fmaf(PX, W1[k0],                                    \
                           fmaf(PY, W1[64 + k0],                               \
                           fmaf(PZ, W1[128 + k0],                              \
                           fmaf(PW, W1[192 + k0], b1[k0]))));                  \
                float a1 = fmaf(PX, W1[k0 + 1],                                \
                           fmaf(PY, W1[65 + k0],                               \
                           fmaf(PZ, W1[129 + k0],                              \
                           fmaf(PW, W1[193 + k0], b1[k0 + 1]))));              \
                a0 = a0 > 0.f ? a0 : 0.f;                                      \
                a1 = a1 > 0.f ? a1 : 0.f;                                      \
                u32 h0 = rne_hi(a0), h1 = rne_hi(a1);                          \
                float l0 = a0 - __uint_as_float(h0);                           \
                float l1 = a1 - __uint_as_float(h1);                           \
                hp[c] = __builtin_amdgcn_perm(h1, h0, 0x07060302u);            \
                lp[c] = __builtin_amdgcn_perm(__float_as_uint(l1),             \
                                              __float_as_uint(l0), 0x07060302u);\
            }                                                                  \
            u32x4 vh = {hp[0], hp[1], hp[2], hp[3]};                           \
            u32x4 vl = {lp[0], lp[1], lp[2], lp[3]};                           \
            *(u32x4*)(Hw + h * 4)        = vh;                                 \
            *(u32x4*)(Hw + 2304 + h * 4) = vl;                                 \
        }                                                                      \
    }

    // prologue: stage group 0, prefetch coords for group 1
    {
        const int gp = p0 + point;
        float px = x[(size_t)gp * 3 + 0], py = x[(size_t)gp * 3 + 1];
        float pz = x[(size_t)gp * 3 + 2], pw = s[gp];
        STAGE_GROUP(0, px, py, pz, pw)
    }
    float pxn, pyn, pzn, pwn;
    {
        const int gp = p0 + 64 + point;
        pxn = x[(size_t)gp * 3 + 0]; pyn = x[(size_t)gp * 3 + 1];
        pzn = x[(size_t)gp * 3 + 2]; pwn = s[gp];
    }

    #pragma unroll 1
    for (int g = 0; g < 8; ++g) {
        __syncthreads();   // buf[g&1] ready for all waves
        const u32* Hb = &Hlds[(g & 1) * 4608];
        f32x16 acc0 = {}, acc1 = {};
        __builtin_amdgcn_s_setprio(1);
        #pragma unroll
        for (int sl = 0; sl < 4; ++sl) {
            s16x8 ahi0 = *(const s16x8*)(Hb + cl * 36 + sl * 8 + kg * 4);
            s16x8 alo0 = *(const s16x8*)(Hb + 2304 + cl * 36 + sl * 8 + kg * 4);
            acc0 = __builtin_amdgcn_mfma_f32_32x32x16_bf16(ahi0, wh[sl], acc0, 0, 0, 0);
            acc0 = __builtin_amdgcn_mfma_f32_32x32x16_bf16(ahi0, wl[sl], acc0, 0, 0, 0);
            acc0 = __builtin_amdgcn_mfma_f32_32x32x16_bf16(alo0, wh[sl], acc0, 0, 0, 0);
            s16x8 ahi1 = *(const s16x8*)(Hb + (32 + cl) * 36 + sl * 8 + kg * 4);
            s16x8 alo1 = *(const s16x8*)(Hb + 2304 + (32 + cl) * 36 + sl * 8 + kg * 4);
            acc1 = __builtin_amdgcn_mfma_f32_32x32x16_bf16(ahi1, wh[sl], acc1, 0, 0, 0);
            acc1 = __builtin_amdgcn_mfma_f32_32x32x16_bf16(ahi1, wl[sl], acc1, 0, 0, 0);
            acc1 = __builtin_amdgcn_mfma_f32_32x32x16_bf16(alo1, wh[sl], acc1, 0, 0, 0);
        }
        __builtin_amdgcn_s_setprio(0);
        // overlap region: stage g+1 (VALU) + issue coords g+2 while MFMA drains
        if (g < 7) {
            STAGE_GROUP(g + 1, pxn, pyn, pzn, pwn)
            if (g < 6) {
                const int gp = p0 + (g + 2) * 64 + point;
                pxn = x[(size_t)gp * 3 + 0]; pyn = x[(size_t)gp * 3 + 1];
                pzn = x[(size_t)gp * 3 + 2]; pwn = s[gp];
            }
        }
        // rmax last: first acc read, after the overlap work
        #pragma unroll
        for (int r = 0; r < 16; ++r)
            rmax = fmaxf(rmax, fmaxf(acc0[r], acc1[r]));
    }
#undef STAGE_GROUP

    rmax = fmaxf(rmax, __shfl_xor(rmax, 32, 64));
    if (lane < 32)
        ws_part[blockIdx.x * 128 + kq * 32 + cl] = rmax;   // block partial max
}

// Hidden layer: block = (batch, 64-unit chunk); thread = (unit, i-quarter).
// comb[0..127] = max over the batch's 16 block-partials (+ b2 fold-in).
__global__ __launch_bounds__(256) void k2a_hidden(
    const float* __restrict__ ws_part, const float* __restrict__ b2,
    const float* __restrict__ e,
    const float* __restrict__ W3, const float* __restrict__ b3,
    float* __restrict__ ws_hid)
{
    const int blk = blockIdx.x;        // 256 = 64 batches x 4 chunks
    const int b   = blk >> 2;
    const int c   = blk & 3;
    const int tid = threadIdx.x;
    const int u   = tid & 63;
    const int part = tid >> 6;         // 0..3, i-range quarter
    __shared__ float comb[640];
    __shared__ float psum[4][64];

    for (int i = tid; i < 640; i += 256) {
        float v;
        if (i < 128) {
            const float* __restrict__ pp = ws_part + (size_t)b * 16 * 128 + i;
            float m = pp[0];
            #pragma unroll
            for (int t = 1; t < 16; ++t) m = fmaxf(m, pp[t * 128]);
            v = m + b2[i];
        } else {
            v = e[b * 512 + (i - 128)];
        }
        comb[i] = v;
    }
    __syncthreads();

    const int gu = c * 64 + u;
    const float* __restrict__ Wp = W3 + (size_t)(part * 160) * 256 + gu;
    const float* __restrict__ cp = comb + part * 160;
    float a = 0.f;
    for (int i = 0; i < 160; ++i) a = fmaf(cp[i], Wp[(size_t)i * 256], a);
    psum[part][u] = a;
    __syncthreads();
    if (tid < 64) {
        float hv = psum[0][u] + psum[1][u] + psum[2][u] + psum[3][u] + b3[gu];
        ws_hid[b * 256 + gu] = hv > 0.f ? hv : 0.f;
    }
}

// z_e + VQ + per-batch loss partial. 64 blocks x 512 threads.
__global__ __launch_bounds__(512) void k2b_vq(
    const float* __restrict__ ws_hid,
    const float* __restrict__ W4, const float* __restrict__ b4,
    const float* __restrict__ cb, float* __restrict__ out,
    float* __restrict__ ws_loss)
{
    const int b = blockIdx.x, tid = threadIdx.x;
    __shared__ float hid[256];
    __shared__ float psum[4][128];
    __shared__ float ze[128];
    __shared__ float red_d[512];
    __shared__ int   red_i[512];
    __shared__ float lred[128];
    __shared__ float zzs;

    if (tid < 256) hid[tid] = ws_hid[b * 256 + tid];
    __syncthreads();

    {
        const int u = tid & 127, part = tid >> 7;
        const float* __restrict__ Wp = W4 + (size_t)(part * 64) * 128 + u;
        const float* __restrict__ hp = hid + part * 64;
        float a = 0.f;
        for (int i = 0; i < 64; ++i) a = fmaf(hp[i], Wp[(size_t)i * 128], a);
        psum[part][u] = a;
    }
    __syncthreads();
    if (tid < 128) {
        float a = psum[0][tid] + psum[1][tid] + psum[2][tid] + psum[3][tid] + b4[tid];
        ze[tid] = a;
        out[8192 + b * 128 + tid] = a;     // z_e
    }
    __syncthreads();

    if (tid < 64) {
        float t = ze[tid] * ze[tid] + ze[tid + 64] * ze[tid + 64];
        #pragma unroll
        for (int d = 1; d < 64; d <<= 1) t += __shfl_xor(t, d, 64);
        if (tid == 0) zzs = t;
    }
    __syncthreads();

    {
        float dot = 0.f, cc = 0.f;
        const f32x4* __restrict__ cp = (const f32x4*)(cb + (size_t)tid * 128);
        for (int k4 = 0; k4 < 32; ++k4) {
            f32x4 v = cp[k4];
            dot = fmaf(ze[k4 * 4 + 0], v.x, dot);
            cc  = fmaf(v.x, v.x, cc);
            dot = fmaf(ze[k4 * 4 + 1], v.y, dot);
            cc  = fmaf(v.y, v.y, cc);
            dot = fmaf(ze[k4 * 4 + 2], v.z, dot);
            cc  = fmaf(v.z, v.z, cc);
            dot = fmaf(ze[k4 * 4 + 3], v.w, dot);
            cc  = fmaf(v.w, v.w, cc);
        }
        red_d[tid] = zzs - 2.f * dot + cc;
        red_i[tid] = tid;
    }
    __syncthreads();

    for (int sft = 256; sft >= 1; sft >>= 1) {
        if (tid < sft) {
            float da = red_d[tid], db = red_d[tid + sft];
            int   ia = red_i[tid], ib = red_i[tid + sft];
            if (db < da || (db == da && ib < ia)) { red_d[tid] = db; red_i[tid] = ib; }
        }
        __syncthreads();
    }
    const int bc = red_i[0];

    if (tid < 128) {
        float zq  = cb[(size_t)bc * 128 + tid];
        float zev = ze[tid];
        out[b * 128 + tid] = zev + (zq - zev);   // z_q_st
        float d = zq - zev;
        lred[tid] = d * d;
    }
    if (tid == 0) out[16386 + b] = (float)bc;
    __syncthreads();
    if (tid < 64) {
        float t = lred[tid] + lred[tid + 64];
        #pragma unroll
        for (int d = 1; d < 64; d <<= 1) t += __shfl_xor(t, d, 64);
        if (tid == 0) ws_loss[b] = t;
    }
}

// Single-wave loss finalize.
__global__ void k3_loss(const float* __restrict__ ws_loss, float* __restrict__ out)
{
    const int t = threadIdx.x;   // 64 threads
    float v = ws_loss[t];
    #pragma unroll
    for (int d = 1; d < 64; d <<= 1) v += __shfl_xor(v, d, 64);
    if (t == 0) {
        float m = v / 8192.f;
        out[16384] = m;   // codebook_loss
        out[16385] = m;   // commitment_loss (numerically identical)
    }
}

extern "C" void kernel_launch(void* const* d_in, const int* in_sizes, int n_in,
                              void* d_out, int out_size, void* d_ws, size_t ws_size,
                              hipStream_t stream) {
    const float* x  = (const float*)d_in[0];
    const float* s  = (const float*)d_in[1];
    const float* e  = (const float*)d_in[2];
    const float* W1 = (const float*)d_in[3];
    const float* b1 = (const float*)d_in[4];
    const float* W2 = (const float*)d_in[5];
    const float* b2 = (const float*)d_in[6];
    const float* W3 = (const float*)d_in[7];
    const float* b3 = (const float*)d_in[8];
    const float* W4 = (const float*)d_in[9];
    const float* b4 = (const float*)d_in[10];
    const float* cb = (const float*)d_in[11];
    float* out = (float*)d_out;

    float* ws_part = (float*)d_ws;                      // 1024*128 f32 = 512 KB
    float* ws_hid  = (float*)d_ws + 1024 * 128;         // 64*256 f32 = 64 KB
    float* ws_loss = (float*)d_ws + 1024 * 128 + 64 * 256;  // 64 f32

    k1_pointfeat<<<1024, 256, 0, stream>>>(x, s, W1, b1, W2, ws_part);
    k2a_hidden<<<256, 256, 0, stream>>>(ws_part, b2, e, W3, b3, ws_hid);
    k2b_vq<<<64, 512, 0, stream>>>(ws_hid, W4, b4, cb, out, ws_loss);
    k3_loss<<<1, 64, 0, stream>>>(ws_loss, out);
}

// Round 9
// 47.417 us; speedup vs baseline: 1.8750x; 1.0754x over previous
//
#include <hip/hip_runtime.h>

typedef unsigned int u32;
typedef __attribute__((ext_vector_type(4))) unsigned int u32x4;
typedef __attribute__((ext_vector_type(8))) short s16x8;
typedef __attribute__((ext_vector_type(4))) float f32x4;

// bf16 RNE of a, returned as f32 bit pattern (low 16 cleared)
__device__ __forceinline__ u32 rne_hi(float a) {
    u32 u = __float_as_uint(a);
    return (u + 0x7FFFu + ((u >> 16) & 1u)) & 0xFFFF0000u;
}

// Round-9 k1: same staging/pipeline as round 8, but layer-2 MFMA switched to
// 16x16x32 with 8 independent accumulator chains (4 m-tiles x 2 n-tiles),
// round-robin issue. Rounds 6-8 were invariant at ~40us across spill removal
// and pipelining; the invariant was the 2-chain x 12-deep 32x32 MFMA
// structure (8-cyc same-chain reuse << dep latency). 8 chains x 6-deep gives
// ~40cyc reuse distance.
__global__ __launch_bounds__(256, 4) void k1_pointfeat(
    const float* __restrict__ x, const float* __restrict__ s,
    const float* __restrict__ W1, const float* __restrict__ b1,
    const float* __restrict__ W2, float* __restrict__ ws_part)
{
    __shared__ __align__(16) u32 Hlds[2 * 2 * 64 * 36];
    const int tid   = threadIdx.x;
    const int lane  = tid & 63;
    const int point = tid & 63;
    const int kq    = __builtin_amdgcn_readfirstlane(tid >> 6); // wave = 32-feature tile
    const int rl    = lane & 15;    // 16x16 row/col lane id
    const int kg2   = lane >> 4;    // 0..3, k-group of 8

    const int p0 = blockIdx.x * 512;

    // W2 B-frags for features kq*32 + n*16 + rl, n in {0,1}, slab in {0,1}:
    // lane holds k = kg2*8 + j + slab*32. hi/lo split. 32 regs resident.
    s16x8 wbh[2][2], wbl[2][2];
    #pragma unroll
    for (int n = 0; n < 2; ++n)
        #pragma unroll
        for (int sl2 = 0; sl2 < 2; ++sl2)
            #pragma unroll
            for (int j = 0; j < 8; ++j) {
                float f = W2[(size_t)(kg2 * 8 + j + sl2 * 32) * 128 + kq * 32 + n * 16 + rl];
                u32 hb = rne_hi(f);
                float lo = f - __uint_as_float(hb);
                u32 lb = rne_hi(lo);
                wbh[n][sl2][j] = (short)(hb >> 16);
                wbl[n][sl2][j] = (short)(lb >> 16);
            }

    float rmax0 = -3.402823466e38f, rmax1 = -3.402823466e38f;

#define STAGE_GROUP(GG, PX, PY, PZ, PW)                                        \
    {                                                                          \
        u32* Hw = &Hlds[((GG) & 1) * 4608 + point * 36 + kq * 8];              \
        _Pragma("unroll")                                                      \
        for (int h = 0; h < 2; ++h) {                                          \
            u32 hp[4], lp[4];                                                  \
            _Pragma("unroll")                                                  \
            for (int c = 0; c < 4; ++c) {                                      \
                const int k0 = kq * 16 + h * 8 + c * 2;                        \
                float a0 = fmaf(PX, W1[k0],                                    \
                           fmaf(PY, W1[64 + k0],                               \
                           fmaf(PZ, W1[128 + k0],                              \
                           fmaf(PW, W1[192 + k0], b1[k0]))));                  \
                float a1 = fmaf(PX, W1[k0 + 1],                                \
                           fmaf(PY, W1[65 + k0],                               \
                           fmaf(PZ, W1[129 + k0],                              \
                           fmaf(PW, W1[193 + k0], b1[k0 + 1]))));              \
                a0 = a0 > 0.f ? a0 : 0.f;                                      \
                a1 = a1 > 0.f ? a1 : 0.f;                                      \
                u32 h0 = rne_hi(a0), h1 = rne_hi(a1);                          \
                float l0 = a0 - __uint_as_float(h0);                           \
                float l1 = a1 - __uint_as_float(h1);                           \
                hp[c] = __builtin_amdgcn_perm(h1, h0, 0x07060302u);            \
                lp[c] = __builtin_amdgcn_perm(__float_as_uint(l1),             \
                                              __float_as_uint(l0), 0x07060302u);\
            }                                                                  \
            u32x4 vh = {hp[0], hp[1], hp[2], hp[3]};                           \
            u32x4 vl = {lp[0], lp[1], lp[2], lp[3]};                           \
            *(u32x4*)(Hw + h * 4)        = vh;                                 \
            *(u32x4*)(Hw + 2304 + h * 4) = vl;                                 \
        }                                                                      \
    }

    // prologue: stage group 0, prefetch coords for group 1
    {
        const int gp = p0 + point;
        float px = x[(size_t)gp * 3 + 0], py = x[(size_t)gp * 3 + 1];
        float pz = x[(size_t)gp * 3 + 2], pw = s[gp];
        STAGE_GROUP(0, px, py, pz, pw)
    }
    float pxn, pyn, pzn, pwn;
    {
        const int gp = p0 + 64 + point;
        pxn = x[(size_t)gp * 3 + 0]; pyn = x[(size_t)gp * 3 + 1];
        pzn = x[(size_t)gp * 3 + 2]; pwn = s[gp];
    }

    #pragma unroll 1
    for (int g = 0; g < 8; ++g) {
        __syncthreads();   // buf[g&1] staged by all waves
        const u32* Hb = &Hlds[(g & 1) * 4608];
        f32x4 acc[4][2] = {};   // [m-tile][n-tile], 8 independent chains
        __builtin_amdgcn_s_setprio(1);
        #pragma unroll
        for (int sl2 = 0; sl2 < 2; ++sl2) {
            // A-frags for this k-slab: point = m*16+rl, k = kg2*8 (+slab*32)
            s16x8 ah[4], al[4];
            #pragma unroll
            for (int m = 0; m < 4; ++m) {
                const u32* base = Hb + (m * 16 + rl) * 36 + sl2 * 16 + kg2 * 4;
                ah[m] = *(const s16x8*)(base);
                al[m] = *(const s16x8*)(base + 2304);
            }
            // pass 1: ah x wbh  (round-robin over 8 chains)
            #pragma unroll
            for (int m = 0; m < 4; ++m)
                #pragma unroll
                for (int n = 0; n < 2; ++n)
                    acc[m][n] = __builtin_amdgcn_mfma_f32_16x16x32_bf16(
                        ah[m], wbh[n][sl2], acc[m][n], 0, 0, 0);
            // pass 2: ah x wbl
            #pragma unroll
            for (int m = 0; m < 4; ++m)
                #pragma unroll
                for (int n = 0; n < 2; ++n)
                    acc[m][n] = __builtin_amdgcn_mfma_f32_16x16x32_bf16(
                        ah[m], wbl[n][sl2], acc[m][n], 0, 0, 0);
            // pass 3: al x wbh
            #pragma unroll
            for (int m = 0; m < 4; ++m)
                #pragma unroll
                for (int n = 0; n < 2; ++n)
                    acc[m][n] = __builtin_amdgcn_mfma_f32_16x16x32_bf16(
                        al[m], wbh[n][sl2], acc[m][n], 0, 0, 0);
        }
        __builtin_amdgcn_s_setprio(0);
        // overlap: stage g+1 (VALU) + issue coords g+2 while MFMAs drain
        if (g < 7) {
            STAGE_GROUP(g + 1, pxn, pyn, pzn, pwn)
            if (g < 6) {
                const int gp = p0 + (g + 2) * 64 + point;
                pxn = x[(size_t)gp * 3 + 0]; pyn = x[(size_t)gp * 3 + 1];
                pzn = x[(size_t)gp * 3 + 2]; pwn = s[gp];
            }
        }
        // rmax last (first acc read = full drain point)
        #pragma unroll
        for (int m = 0; m < 4; ++m)
            #pragma unroll
            for (int r = 0; r < 4; ++r) {
                rmax0 = fmaxf(rmax0, acc[m][0][r]);
                rmax1 = fmaxf(rmax1, acc[m][1][r]);
            }
    }
#undef STAGE_GROUP

    // lanes l, l^16, l^32, l^48 hold the same feature column
    rmax0 = fmaxf(rmax0, __shfl_xor(rmax0, 16, 64));
    rmax0 = fmaxf(rmax0, __shfl_xor(rmax0, 32, 64));
    rmax1 = fmaxf(rmax1, __shfl_xor(rmax1, 16, 64));
    rmax1 = fmaxf(rmax1, __shfl_xor(rmax1, 32, 64));
    if (lane < 16) {
        ws_part[blockIdx.x * 128 + kq * 32 + lane]      = rmax0;
        ws_part[blockIdx.x * 128 + kq * 32 + 16 + lane] = rmax1;
    }
}

// Hidden layer: block = (batch, 64-unit chunk); thread = (unit, i-quarter).
__global__ __launch_bounds__(256) void k2a_hidden(
    const float* __restrict__ ws_part, const float* __restrict__ b2,
    const float* __restrict__ e,
    const float* __restrict__ W3, const float* __restrict__ b3,
    float* __restrict__ ws_hid)
{
    const int blk = blockIdx.x;        // 256 = 64 batches x 4 chunks
    const int b   = blk >> 2;
    const int c   = blk & 3;
    const int tid = threadIdx.x;
    const int u   = tid & 63;
    const int part = tid >> 6;         // 0..3, i-range quarter
    __shared__ float comb[640];
    __shared__ float psum[4][64];

    for (int i = tid; i < 640; i += 256) {
        float v;
        if (i < 128) {
            const float* __restrict__ pp = ws_part + (size_t)b * 16 * 128 + i;
            float m = pp[0];
            #pragma unroll
            for (int t = 1; t < 16; ++t) m = fmaxf(m, pp[t * 128]);
            v = m + b2[i];
        } else {
            v = e[b * 512 + (i - 128)];
        }
        comb[i] = v;
    }
    __syncthreads();

    const int gu = c * 64 + u;
    const float* __restrict__ Wp = W3 + (size_t)(part * 160) * 256 + gu;
    const float* __restrict__ cp = comb + part * 160;
    float a = 0.f;
    for (int i = 0; i < 160; ++i) a = fmaf(cp[i], Wp[(size_t)i * 256], a);
    psum[part][u] = a;
    __syncthreads();
    if (tid < 64) {
        float hv = psum[0][u] + psum[1][u] + psum[2][u] + psum[3][u] + b3[gu];
        ws_hid[b * 256 + gu] = hv > 0.f ? hv : 0.f;
    }
}

// z_e + VQ + per-batch loss partial. 64 blocks x 512 threads.
__global__ __launch_bounds__(512) void k2b_vq(
    const float* __restrict__ ws_hid,
    const float* __restrict__ W4, const float* __restrict__ b4,
    const float* __restrict__ cb, float* __restrict__ out,
    float* __restrict__ ws_loss)
{
    const int b = blockIdx.x, tid = threadIdx.x;
    __shared__ float hid[256];
    __shared__ float psum[4][128];
    __shared__ float ze[128];
    __shared__ float red_d[512];
    __shared__ int   red_i[512];
    __shared__ float lred[128];
    __shared__ float zzs;

    if (tid < 256) hid[tid] = ws_hid[b * 256 + tid];
    __syncthreads();

    {
        const int u = tid & 127, part = tid >> 7;
        const float* __restrict__ Wp = W4 + (size_t)(part * 64) * 128 + u;
        const float* __restrict__ hp = hid + part * 64;
        float a = 0.f;
        for (int i = 0; i < 64; ++i) a = fmaf(hp[i], Wp[(size_t)i * 128], a);
        psum[part][u] = a;
    }
    __syncthreads();
    if (tid < 128) {
        float a = psum[0][tid] + psum[1][tid] + psum[2][tid] + psum[3][tid] + b4[tid];
        ze[tid] = a;
        out[8192 + b * 128 + tid] = a;     // z_e
    }
    __syncthreads();

    if (tid < 64) {
        float t = ze[tid] * ze[tid] + ze[tid + 64] * ze[tid + 64];
        #pragma unroll
        for (int d = 1; d < 64; d <<= 1) t += __shfl_xor(t, d, 64);
        if (tid == 0) zzs = t;
    }
    __syncthreads();

    {
        float dot = 0.f, cc = 0.f;
        const f32x4* __restrict__ cp = (const f32x4*)(cb + (size_t)tid * 128);
        for (int k4 = 0; k4 < 32; ++k4) {
            f32x4 v = cp[k4];
            dot = fmaf(ze[k4 * 4 + 0], v.x, dot);
            cc  = fmaf(v.x, v.x, cc);
            dot = fmaf(ze[k4 * 4 + 1], v.y, dot);
            cc  = fmaf(v.y, v.y, cc);
            dot = fmaf(ze[k4 * 4 + 2], v.z, dot);
            cc  = fmaf(v.z, v.z, cc);
            dot = fmaf(ze[k4 * 4 + 3], v.w, dot);
            cc  = fmaf(v.w, v.w, cc);
        }
        red_d[tid] = zzs - 2.f * dot + cc;
        red_i[tid] = tid;
    }
    __syncthreads();

    for (int sft = 256; sft >= 1; sft >>= 1) {
        if (tid < sft) {
            float da = red_d[tid], db = red_d[tid + sft];
            int   ia = red_i[tid], ib = red_i[tid + sft];
            if (db < da || (db == da && ib < ia)) { red_d[tid] = db; red_i[tid] = ib; }
        }
        __syncthreads();
    }
    const int bc = red_i[0];

    if (tid < 128) {
        float zq  = cb[(size_t)bc * 128 + tid];
        float zev = ze[tid];
        out[b * 128 + tid] = zev + (zq - zev);   // z_q_st
        float d = zq - zev;
        lred[tid] = d * d;
    }
    if (tid == 0) out[16386 + b] = (float)bc;
    __syncthreads();
    if (tid < 64) {
        float t = lred[tid] + lred[tid + 64];
        #pragma unroll
        for (int d = 1; d < 64; d <<= 1) t += __shfl_xor(t, d, 64);
        if (tid == 0) ws_loss[b] = t;
    }
}

// Single-wave loss finalize.
__global__ void k3_loss(const float* __restrict__ ws_loss, float* __restrict__ out)
{
    const int t = threadIdx.x;   // 64 threads
    float v = ws_loss[t];
    #pragma unroll
    for (int d = 1; d < 64; d <<= 1) v += __shfl_xor(v, d, 64);
    if (t == 0) {
        float m = v / 8192.f;
        out[16384] = m;   // codebook_loss
        out[16385] = m;   // commitment_loss (numerically identical)
    }
}

extern "C" void kernel_launch(void* const* d_in, const int* in_sizes, int n_in,
                              void* d_out, int out_size, void* d_ws, size_t ws_size,
                              hipStream_t stream) {
    const float* x  = (const float*)d_in[0];
    const float* s  = (const float*)d_in[1];
    const float* e  = (const float*)d_in[2];
    const float* W1 = (const float*)d_in[3];
    const float* b1 = (const float*)d_in[4];
    const float* W2 = (const float*)d_in[5];
    const float* b2 = (const float*)d_in[6];
    const float* W3 = (const float*)d_in[7];
    const float* b3 = (const float*)d_in[8];
    const float* W4 = (const float*)d_in[9];
    const float* b4 = (const float*)d_in[10];
    const float* cb = (const float*)d_in[11];
    float* out = (float*)d_out;

    float* ws_part = (float*)d_ws;                      // 1024*128 f32 = 512 KB
    float* ws_hid  = (float*)d_ws + 1024 * 128;         // 64*256 f32 = 64 KB
    float* ws_loss = (float*)d_ws + 1024 * 128 + 64 * 256;  // 64 f32

    k1_pointfeat<<<1024, 256, 0, stream>>>(x, s, W1, b1, W2, ws_part);
    k2a_hidden<<<256, 256, 0, stream>>>(ws_part, b2, e, W3, b3, ws_hid);
    k2b_vq<<<64, 512, 0, stream>>>(ws_hid, W4, b4, cb, out, ws_loss);
    k3_loss<<<1, 64, 0, stream>>>(ws_loss, out);
}